// Round 17
// baseline (117.730 us; speedup 1.0000x reference)
//
#include <hip/hip_runtime.h>
#include <hip/hip_bf16.h>
#include <cstdint>

// Problem constants
#define BROWS 8192
#define DIN   512
#define DH    1024
#define KTOT  1536          // DIN + DH
#define NT    (KTOT / 64)   // 24 K-tiles of 64
// Only gate columns [0,2048) are live: g block [0,1024), i block [1024,2048).
// (reference bug: f_out and o_out both use i_in -> f_in/o_in are dead)

typedef __bf16 bf16x8 __attribute__((ext_vector_type(8)));
typedef __bf16 bf16x4 __attribute__((ext_vector_type(4)));
typedef float  f32x16 __attribute__((ext_vector_type(16)));

__device__ __forceinline__ void load16_to_lds(const void* gptr, void* lptr) {
    __builtin_amdgcn_global_load_lds(
        (const __attribute__((address_space(1))) uint32_t*)gptr,
        (__attribute__((address_space(3))) uint32_t*)lptr,
        16, 0, 0);
}

// ---------- Kernel 1: MERGED conversion pass ----------
// blocks [0,6144): x|h -> bf16 A[8192][1536], pre-swizzled (R4-proven XOR-8).
// blocks [6144,9216): W cols [0,2048) transpose -> bf16 Bt[2048][1536], swizzled.
__global__ __launch_bounds__(256) void cvt_kernel(
    const float* __restrict__ x, const float* __restrict__ h,
    const float* __restrict__ Wx, const float* __restrict__ Wh,
    __bf16* __restrict__ A, __bf16* __restrict__ Bt) {
    __shared__ float tile[32][33];
    const int b = blockIdx.x;
    if (b < 6144) {
        int t = b * 256 + threadIdx.x;            // 8192*192 units of 16B
        int row = t / 192;
        int j = t - row * 192;
        int kg = j * 8;
        const float* src = (kg < DIN) ? (x + (size_t)row * DIN + kg)
                                      : (h + (size_t)row * DH + (kg - DIN));
        float4 u = *(const float4*)src;
        float4 v = *(const float4*)(src + 4);
        bf16x8 o = { (__bf16)u.x, (__bf16)u.y, (__bf16)u.z, (__bf16)u.w,
                     (__bf16)v.x, (__bf16)v.y, (__bf16)v.z, (__bf16)v.w };
        int swz = (j * 16) ^ ((row & 7) << 4);
        *(bf16x8*)((char*)A + (size_t)row * 3072 + swz) = o;
    } else {
        int bb = b - 6144;                        // 0..3071
        int k0 = (bb % 48) * 32;
        int n0 = (bb / 48) * 32;
        int tx = threadIdx.x & 31;
        int ty = threadIdx.x >> 5;                // 0..7
#pragma unroll
        for (int i = 0; i < 4; ++i) {
            int k = k0 + ty + 8 * i;
            float v = (k < DIN) ? Wx[(size_t)k * 4096 + n0 + tx]
                                : Wh[(size_t)(k - DIN) * 4096 + n0 + tx];
            tile[ty + 8 * i][tx] = v;
        }
        __syncthreads();
        int n = n0 + tx;
        int kk = ty * 4;
        bf16x4 o = { (__bf16)tile[kk][tx], (__bf16)tile[kk + 1][tx],
                     (__bf16)tile[kk + 2][tx], (__bf16)tile[kk + 3][tx] };
        int swz = ((k0 + kk) * 2) ^ ((n & 7) << 4);
        *(bf16x4*)((char*)Bt + (size_t)n * 3072 + swz) = o;
    }
}

// ---------- Kernel 2: R15 chassis (32x32x16 MFMA) + c_in prefetch epilogue ----------
#define BARRIER  do { __builtin_amdgcn_sched_barrier(0); __builtin_amdgcn_s_barrier(); __builtin_amdgcn_sched_barrier(0); } while (0)
#define VMW(n)   do { asm volatile("s_waitcnt vmcnt(" #n ")" ::: "memory"); __builtin_amdgcn_sched_barrier(0); } while (0)
#define LGKM0    do { asm volatile("s_waitcnt lgkmcnt(0)" ::: "memory"); __builtin_amdgcn_sched_barrier(0); } while (0)

#define STAGE_A(buf, mh, kt) do {                                              \
    const char* g0_ = Ab + (size_t)(brow + (mh) * 128 + r0) * 3072             \
                         + (size_t)(kt) * 128 + cb;                            \
    char* l0_ = sAb + (buf) * 32768 + ((mh) * 128 + r0) * 128 + cb;            \
    load16_to_lds(g0_, l0_);                                                   \
    load16_to_lds(g0_ + 64 * 3072, l0_ + 64 * 128);                            \
} while (0)

#define STAGE_B(buf, half, kt) do {                                            \
    const char* g0_ = Bb + (size_t)((half) * 1024 + bnp + r0) * 3072           \
                         + (size_t)(kt) * 128 + cb;                            \
    char* l0_ = sBb + (buf) * 32768 + ((half) * 128 + r0) * 128 + cb;          \
    load16_to_lds(g0_, l0_);                                                   \
    load16_to_lds(g0_ + 64 * 3072, l0_ + 64 * 128);                            \
} while (0)

// 32x32x16 A-frag: lane l -> row l&31, k-half l>>5 (R15-verified)
#define READ_A32(dst, c, mh)                                                   \
    _Pragma("unroll")                                                          \
    for (int kf_ = 0; kf_ < 4; ++kf_) {                                        \
        int row_ = wrow + (mh) * 32 + l31;                                     \
        int kb_ = (kf_ * 32 + hi16) ^ ((l31 & 7) << 4);                        \
        dst[kf_] = *(const bf16x8*)(sAb + (c) * 32768 + row_ * 128 + kb_);     \
    }

#define READ_B32(dst, c, half)                                                 \
    _Pragma("unroll")                                                          \
    for (int nq_ = 0; nq_ < 2; ++nq_) {                                        \
        _Pragma("unroll")                                                      \
        for (int kf_ = 0; kf_ < 4; ++kf_) {                                    \
            int row_ = (half) * 128 + wcol + nq_ * 32 + l31;                   \
            int kb_ = (kf_ * 32 + hi16) ^ ((l31 & 7) << 4);                    \
            dst[nq_][kf_] = *(const bf16x8*)(sBb + (c) * 32768 + row_ * 128    \
                                             + kb_);                           \
        }                                                                      \
    }

#define MMA32(ACC, MH, AF, BF) do {                                            \
    __builtin_amdgcn_s_setprio(1);                                             \
    _Pragma("unroll")                                                          \
    for (int kf_ = 0; kf_ < 4; ++kf_) {                                        \
        _Pragma("unroll")                                                      \
        for (int nq_ = 0; nq_ < 2; ++nq_) {                                    \
            ACC[MH][nq_] = __builtin_amdgcn_mfma_f32_32x32x16_bf16(            \
                AF[kf_], BF[nq_][kf_], ACC[MH][nq_], 0, 0, 0);                 \
        }                                                                      \
    }                                                                          \
    __builtin_amdgcn_s_setprio(0);                                             \
    __builtin_amdgcn_sched_barrier(0);                                         \
} while (0)

__global__ __launch_bounds__(512) void lstm_gemm_kernel(
    const __bf16* __restrict__ A,    // [8192][1536] pre-swizzled
    const __bf16* __restrict__ Bt,   // [2048][1536] pre-swizzled
    const float* __restrict__ bias,  // [4096]
    const float* __restrict__ c_in,  // [8192][1024]
    float* __restrict__ out_h,       // [8192][1024]
    float* __restrict__ out_c) {     // [8192][1024]
    __shared__ __bf16 sA[2][256][64];   // 64 KiB
    __shared__ __bf16 sB[2][256][64];   // 64 KiB (g rows 0-127, i rows 128-255)

    const int tid  = threadIdx.x;
    const int lane = tid & 63;
    const int wid  = tid >> 6;
    const int wr   = wid & 3;          // 4 wave-rows
    const int wc   = wid >> 2;         // 2 wave-cols

    // XCD-contiguous band map (R9-proven: FETCH 67 MB)
    const int bid   = blockIdx.x;              // 0..255
    const int band  = (bid & 7) * 4 + ((bid >> 3) & 3);  // 0..31
    const int panel = bid >> 5;                          // 0..7
    const int brow  = band * 256;
    const int bnp   = panel * 128;

    const int l31  = lane & 31;
    const int hi   = lane >> 5;        // 0..1
    const int hi16 = hi * 16;
    const int wrow = wr * 64;
    const int wcol = wc * 64;

    // staging lane mapping: per wave, LDS dst = uniform base + lane*16
    const int r0 = tid >> 3;           // 0..63
    const int cb = (tid & 7) * 16;     // 0..112

    const char* Ab = (const char*)A;
    const char* Bb = (const char*)Bt;
    char* sAb = (char*)&sA[0][0][0];
    char* sBb = (char*)&sB[0][0][0];

    const int R0 = brow + wrow;
    const int C0 = bnp + wcol;

    f32x16 accg[2][2], acci[2][2];
#pragma unroll
    for (int mh = 0; mh < 2; ++mh)
#pragma unroll
        for (int nq = 0; nq < 2; ++nq)
#pragma unroll
            for (int j = 0; j < 16; ++j) {
                accg[mh][nq][j] = 0.f;
                acci[mh][nq][j] = 0.f;
            }

    bf16x8 aF0[4], aF1[4], bgF[2][4], biF[2][4];
    float cpre[2][2][16];              // c_in prefetch (static idx, rule #20)

    // prologue: stage tile 0.  Queue order per tile: A0, A1, Bg, Bi.
    STAGE_A(0, 0, 0);
    STAGE_A(0, 1, 0);
    STAGE_B(0, 0, 0);
    STAGE_B(0, 1, 0);

    for (int t = 0; t < NT - 1; ++t) {
        const int c  = t & 1;
        const int nb = c ^ 1;
        // P1: needs A0, A1, Bg of tile t  (oldest 6 of 8 in flight)
        VMW(2); BARRIER;
        READ_A32(aF0, c, 0);
        READ_B32(bgF, c, 0);
        STAGE_A(nb, 0, t + 1);
        BARRIER; LGKM0;
        MMA32(accg, 0, aF0, bgF);
        // P2: no new LDS data needed
        BARRIER;
        READ_A32(aF1, c, 1);
        STAGE_A(nb, 1, t + 1);
        BARRIER; LGKM0;
        MMA32(accg, 1, aF1, bgF);
        // P3: needs Bi of tile t  (queue: [Bi(t), A0(t+1), A1(t+1)] = 6)
        VMW(4); BARRIER;
        READ_B32(biF, c, 1);
        STAGE_B(nb, 0, t + 1);
        BARRIER; LGKM0;
        MMA32(acci, 0, aF0, biF);
        // P4: nothing new needed
        BARRIER;
        STAGE_B(nb, 1, t + 1);
        BARRIER;
        MMA32(acci, 1, aF1, biF);
    }
    {   // last tile: exact drains 2 -> 0; c_in prefetch after final drain
        const int c = (NT - 1) & 1;
        VMW(2); BARRIER;
        READ_A32(aF0, c, 0);
        READ_B32(bgF, c, 0);
        BARRIER; LGKM0;
        MMA32(accg, 0, aF0, bgF);
        BARRIER;
        READ_A32(aF1, c, 1);
        BARRIER; LGKM0;
        MMA32(accg, 1, aF1, bgF);
        VMW(0); BARRIER;
        // issue ALL c_in loads now: they fly during the remaining ~3
        // read/MFMA phases; no later counted VMW exists to drain them.
#pragma unroll
        for (int mh = 0; mh < 2; ++mh)
#pragma unroll
            for (int nq = 0; nq < 2; ++nq)
#pragma unroll
                for (int r = 0; r < 16; ++r) {
                    int row = R0 + mh * 32 + (r & 3) + 8 * (r >> 2) + 4 * hi;
                    int col = C0 + nq * 32 + l31;
                    cpre[mh][nq][r] = c_in[(size_t)row * DH + col];
                }
        READ_B32(biF, c, 1);
        BARRIER; LGKM0;
        MMA32(acci, 0, aF0, biF);
        MMA32(acci, 1, aF1, biF);
    }

    // Epilogue. 32x32 C/D layout (m74/m101): col = lane&31,
    // row = (r&3) + 8*(r>>2) + 4*(lane>>5), r in [0,16).
#pragma unroll
    for (int nq = 0; nq < 2; ++nq) {
        const int col = C0 + nq * 32 + l31;
        const float bg = bias[col];
        const float bi = bias[1024 + col];
#pragma unroll
        for (int mh = 0; mh < 2; ++mh) {
#pragma unroll
            for (int r = 0; r < 16; ++r) {
                const int row = R0 + mh * 32 + (r & 3) + 8 * (r >> 2) + 4 * hi;
                const float g_in = accg[mh][nq][r] + bg;
                const float i_in = acci[mh][nq][r] + bi;
                const float s  = 1.0f / (1.0f + __expf(-i_in));
                const float tg = 2.0f / (1.0f + __expf(-2.0f * g_in)) - 1.0f;
                const float cv = cpre[mh][nq][r];
                const float cn = s * (tg + cv);
                const float hn = (2.0f / (1.0f + __expf(-2.0f * cn)) - 1.0f) * s;
                out_h[(size_t)row * DH + col] = hn;
                out_c[(size_t)row * DH + col] = cn;
            }
        }
    }
}

extern "C" void kernel_launch(void* const* d_in, const int* in_sizes, int n_in,
                              void* d_out, int out_size, void* d_ws, size_t ws_size,
                              hipStream_t stream) {
    const float* x  = (const float*)d_in[0];
    const float* h  = (const float*)d_in[1];
    const float* c  = (const float*)d_in[2];
    const float* Wx = (const float*)d_in[3];
    const float* Wh = (const float*)d_in[4];
    const float* b  = (const float*)d_in[5];

    __bf16* A  = (__bf16*)d_ws;                                     // 25,165,824 B
    __bf16* Bt = (__bf16*)((char*)d_ws + (size_t)BROWS * KTOT * 2); // 6,291,456 B

    float* out_h = (float*)d_out;
    float* out_c = out_h + (size_t)BROWS * DH;

    cvt_kernel<<<9216, 256, 0, stream>>>(x, h, Wx, Wh, A, Bt);
    lstm_gemm_kernel<<<256, 512, 0, stream>>>(A, Bt, b, c, out_h, out_c);
}